// Round 8
// baseline (2780.475 us; speedup 1.0000x reference)
//
#include <hip/hip_runtime.h>
#include <math.h>

#define B_   8
#define NIN  20000
#define NALL 1200
#define NPTQ 1024
#define KNB  34
#define CH   96
#define FF   384
#define NQ   (B_ * NPTQ)   // 8192

#define FT   1024          // FPS threads per block
#define NPRZ 10            // z/dist float2 pairs per thread: 2*10*1024 = 20480 slots
#define NWAVE (FT / 64)    // 16 waves

typedef unsigned int   u32;
typedef unsigned long long u64;
typedef float v2f __attribute__((ext_vector_type(2)));

// Fast-math-proof non-finite check (integer ops can't be folded away).
__device__ __forceinline__ float scrub(float f) {
    u32 u = __float_as_uint(f);
    return ((u & 0x7F800000u) == 0x7F800000u) ? 12345.0f : f;   // diagnostic sentinel
}

// ---------------------------------------------------------------------------
// 1. Farthest point sampling: one block per batch (rounds 1-4: cross-block
//    handshakes >= 2.4us/iter at device scope -- dead end).
//    Rounds 0/5/6/7 lesson: FOUR codegens (remat, asm-pin, waves_per_eu,
//    1024-thread geometry) all landed at ~1.9us/iter because the register
//    allocator never grants enough VGPRs (116/104/104/64) and the point
//    data always round-trips L1/L2 (~200KB/iter @ ~60B/cyc/CU ~= 4000cyc).
//    Fix: stop fighting the RF.  LDS has a GUARANTEED 160KiB budget:
//      - (x,y) of all 20000 points -> LDS (160,000B), ds_read_b64 at
//        stride 1024*8B: lane l hits banks (2l)%32 -> 2 lanes/bank = free
//      - z + dist stay in registers: 40 VGPRs data + ~20 working <= 64,
//        fits even the allocator's stingiest grant -> no spill POSSIBLE
//    Per iter: LDS 160KB@128B/cyc ~= 1280cyc || VALU ~120pk x 4w x 2cyc
//    ~= 960cyc + reduce ~700 -> ~2100cyc ~= 0.88us (was 1.9us).
//    Argmax is value-first (proven r5-7): inner loop tracks the pk max only;
//    index recovered after block max M known by equality scan (exact: min/max
//    return an operand bit-identically) in waves containing M.
//    Exactness: rn ops in numpy order ((sx+sy)+sz, contract off), min/max
//    order-independent; winner = smallest point index among ties
//    (idx = slot*1024 + tid IS the point index) = jnp.argmax first-occurrence.
//    Pads carry dist=-1: min(-1, d)=-1 even for d=NaN/Inf from garbage xy
//    (IEEE v_min returns the non-NaN operand), and -1 never equals M>=0 --
//    so out-of-range LDS slots (20000..20479) are harmless whatever they read.
// ---------------------------------------------------------------------------
__global__ __launch_bounds__(FT, 4)
void fps_kernel(const float* __restrict__ pc, int* __restrict__ fps_idx) {
#pragma clang fp contract(off)
    const int b = blockIdx.x;
    const int tid = threadIdx.x;
    const int lane = tid & 63;
    const int wid = tid >> 6;          // 0..15
    const float* base = pc + (size_t)b * NIN * 3;

    __shared__ v2f sxy[NIN];           // 160,000 B
    __shared__ float wmax[2][NWAVE];   // 128 B
    __shared__ u32 widx_s[2];          // 8 B   -> total 160,136 <= 163,840

    v2f vz[NPRZ], dist[NPRZ];
#pragma unroll
    for (int j = 0; j < NPRZ; ++j) {
        int i0 = tid + (2 * j) * FT;   // even slot: max 19455, always valid
        int i1 = i0 + FT;              // odd slot: max 20479, pad when >= NIN
        bool ok1 = i1 < NIN;
        int a1 = ok1 ? i1 : 0;
        float x0 = base[(size_t)i0 * 3 + 0];
        float y0 = base[(size_t)i0 * 3 + 1];
        float z0 = base[(size_t)i0 * 3 + 2];
        float x1 = base[(size_t)a1 * 3 + 0];
        float y1 = base[(size_t)a1 * 3 + 1];
        float z1 = base[(size_t)a1 * 3 + 2];
        v2f xy0; xy0.x = x0; xy0.y = y0;
        sxy[i0] = xy0;
        if (ok1) { v2f xy1; xy1.x = x1; xy1.y = y1; sxy[i1] = xy1; }
        vz[j].x = z0; vz[j].y = z1;
        dist[j].x = 1e10f;
        dist[j].y = ok1 ? 1e10f : -1.0f;   // pad: never wins, never equals M
    }

    if (tid == 0) {
        widx_s[0] = 0xFFFFFFFFu;
        widx_s[1] = 0xFFFFFFFFu;
        fps_idx[b * NALL + 0] = 0;
    }
    __syncthreads();                       // sxy + widx_s ready
    float cx = base[0], cy = base[1], cz = base[2];

    for (int it = 1; it < NALL; ++it) {
        const int pb = it & 1;
        v2f cxy; cxy.x = cx; cxy.y = cy;   // pk operand for (x,y)
        v2f cvz; cvz.x = cz; cvz.y = cz;
        v2f run; run.x = -1e38f; run.y = -1e38f;
#pragma unroll
        for (int j = 0; j < NPRZ; ++j) {
            v2f xya = sxy[tid + (2 * j) * FT];       // ds_read_b64, 2-way free
            v2f xyb = sxy[tid + (2 * j + 1) * FT];   // j=9 may read pad slots: shielded
            v2f dxa = xya - cxy;                     // {dx,dy} pk sub
            v2f dxb = xyb - cxy;
            v2f sa  = dxa * dxa;                     // {dx2,dy2} pk mul
            v2f sb  = dxb * dxb;
            v2f dz  = vz[j] - cvz;
            v2f sz  = dz * dz;
            v2f d;
            d.x = (sa.x + sa.y) + sz.x;              // exact numpy order, no FMA
            d.y = (sb.x + sb.y) + sz.y;
            v2f nd = __builtin_elementwise_min(dist[j], d);
            dist[j] = nd;
            run = __builtin_elementwise_max(run, nd);
        }
        float lm = fmaxf(run.x, run.y);
        // wave f32 max (6-step butterfly)
        float wm = lm;
#pragma unroll
        for (int s = 32; s; s >>= 1) wm = fmaxf(wm, __shfl_xor(wm, s, 64));
        if (lane == 0) wmax[pb][wid] = wm;
        __syncthreads();                       // barrier 1
        if (tid == 0) widx_s[pb ^ 1] = 0xFFFFFFFFu;  // reset idle buffer (safe here)
        float M = wmax[pb][0];
#pragma unroll
        for (int w = 1; w < NWAVE; ++w) M = fmaxf(M, wmax[pb][w]);

        // index recovery: only waves containing M scan + reduce
        if (__any(lm == M)) {
            u32 msk = 0;
#pragma unroll
            for (int j = 0; j < NPRZ; ++j) {
                if (dist[j].x == M) msk |= (1u << (2 * j));
                if (dist[j].y == M) msk |= (1u << (2 * j + 1));
            }
            // sentinel bit 31: lanes w/o match yield slot 31 -> idx >= 31744,
            // always loses to a real candidate (<= 20479); some lane here has one.
            u32 slot = (u32)__builtin_ctz(msk | 0x80000000u);
            u32 cand = slot * (u32)FT + (u32)tid;    // == global point index
#pragma unroll
            for (int s = 32; s; s >>= 1) {
                u32 o = (u32)__shfl_xor((int)cand, s, 64);
                cand = (o < cand) ? o : cand;
            }
            if (lane == 0) atomicMin(&widx_s[pb], cand);
        }
        __syncthreads();                       // barrier 2
        u32 widx = widx_s[pb];
        widx = (widx < NIN) ? widx : 0;        // defensive (cannot trigger)
        if (tid == 0) fps_idx[b * NALL + it] = (int)widx;
        const float* wp = base + (size_t)widx * 3;
        cx = wp[0]; cy = wp[1]; cz = wp[2];    // same addr all lanes: broadcast
    }
}

// ---------------------------------------------------------------------------
// 2. Gather coords at fps_idx[sel]; fp32 coord workspace + fp32 coord output
// ---------------------------------------------------------------------------
__global__ void gather_kernel(const float* __restrict__ pc,
                              const int* __restrict__ fps_idx, const int* __restrict__ sel,
                              float* __restrict__ coord, float* __restrict__ out_coord) {
    int t = blockIdx.x * 256 + threadIdx.x;
    if (t >= NQ) return;
    int b = t >> 10, j = t & 1023;
    int p = fps_idx[b * NALL + sel[j]];
    p = (p < 0) ? 0 : ((p >= NIN) ? (NIN - 1) : p);   // defensive clamp
    const float* pp = pc + ((size_t)b * NIN + p) * 3;
    float x = pp[0], y = pp[1], z = pp[2];
    coord[(size_t)t * 3 + 0] = x;
    coord[(size_t)t * 3 + 1] = y;
    coord[(size_t)t * 3 + 2] = z;
    out_coord[(size_t)t * 3 + 0] = scrub(x);
    out_coord[(size_t)t * 3 + 1] = scrub(y);
    out_coord[(size_t)t * 3 + 2] = scrub(z);
}

// ---------------------------------------------------------------------------
// 3. kNN within radius: one wave per query, stable (d2, idx) ascending, K=34.
// ---------------------------------------------------------------------------
__global__ void knn_kernel(const float* __restrict__ coord, int* __restrict__ nbr) {
    __shared__ float sx[NPTQ], sy[NPTQ], sz[NPTQ];
    const double RAD2D = (2.5 * 0.04) * (2.5 * 0.04);
    int b = blockIdx.x >> 8;              // 256 blocks per batch
    int i0 = (blockIdx.x & 255) * 4;
    const float* cb = coord + (size_t)b * NPTQ * 3;
    for (int t = threadIdx.x; t < NPTQ; t += 256) {
        sx[t] = cb[(size_t)t * 3 + 0];
        sy[t] = cb[(size_t)t * 3 + 1];
        sz[t] = cb[(size_t)t * 3 + 2];
    }
    __syncthreads();
    int wid = threadIdx.x >> 6, lane = threadIdx.x & 63;
    int i = i0 + wid;
    float qx = sx[i], qy = sy[i], qz = sz[i];
    u64 pk[16];
#pragma unroll
    for (int t = 0; t < 16; ++t) {
        int j = lane + t * 64;
        float dx = __fsub_rn(qx, sx[j]);
        float dy = __fsub_rn(qy, sy[j]);
        float dz = __fsub_rn(qz, sz[j]);
        float d2 = __fadd_rn(__fadd_rn(__fmul_rn(dx, dx), __fmul_rn(dy, dy)),
                             __fmul_rn(dz, dz));
        bool valid = ((double)d2 <= RAD2D);
        pk[t] = valid ? (((u64)__float_as_uint(d2) << 32) | (u32)j) : ~0ull;
    }
    int* out = nbr + ((size_t)b * NPTQ + i) * KNB;
    int k = 0;
    for (; k < KNB; ++k) {
        u64 m = ~0ull;
#pragma unroll
        for (int t = 0; t < 16; ++t) m = (pk[t] < m) ? pk[t] : m;
#pragma unroll
        for (int s = 32; s; s >>= 1) {
            u64 o = __shfl_xor(m, s, 64);
            m = (o < m) ? o : m;
        }
        if (m == ~0ull) break;
#pragma unroll
        for (int t = 0; t < 16; ++t) if (pk[t] == m) pk[t] = ~0ull;
        if (lane == 0) out[k] = (int)(m & 0xFFFFFFFFu);
    }
    for (; k < KNB; ++k) if (lane == 0) out[k] = -1;
}

// ---------------------------------------------------------------------------
// 4. x = [color, coord] @ W_in + b_in  (reads inputs directly via fps_idx/sel)
// ---------------------------------------------------------------------------
__global__ void xproj_kernel(const float* __restrict__ pc, const float* __restrict__ col,
                             const int* __restrict__ fps_idx, const int* __restrict__ sel,
                             const float* __restrict__ Win, const float* __restrict__ bin,
                             float* __restrict__ x) {
    int idx = blockIdx.x * 256 + threadIdx.x;
    if (idx >= NQ * CH) return;
    int q = idx / CH, c = idx - q * CH;
    int b = q >> 10, j = q & 1023;
    int p = fps_idx[b * NALL + sel[j]];
    p = (p < 0) ? 0 : ((p >= NIN) ? (NIN - 1) : p);
    const float* pp = pc + ((size_t)b * NIN + p) * 3;
    const float* cc = col + ((size_t)b * NIN + p) * 3;
    float acc = bin[c];
    acc += cc[0] * Win[0 * CH + c];
    acc += cc[1] * Win[1 * CH + c];
    acc += cc[2] * Win[2 * CH + c];
    acc += pp[0] * Win[3 * CH + c];
    acc += pp[1] * Win[4 * CH + c];
    acc += pp[2] * Win[5 * CH + c];
    x[idx] = acc;
}

// ---------------------------------------------------------------------------
// 5. q,k,v = x @ Wq/Wk/Wv  (computed once per point)
// ---------------------------------------------------------------------------
__global__ void qkv_kernel(const float* __restrict__ x,
                           const float* __restrict__ Wq, const float* __restrict__ Wk,
                           const float* __restrict__ Wv,
                           float* __restrict__ qo, float* __restrict__ ko,
                           float* __restrict__ vo) {
    int idx = blockIdx.x * 256 + threadIdx.x;
    if (idx >= NQ * CH) return;
    int q = idx / CH, c = idx - q * CH;
    const float* xr = x + (size_t)q * CH;
    float aq = 0.f, ak = 0.f, av = 0.f;
    for (int k = 0; k < CH; ++k) {
        float xv = xr[k];
        aq += xv * Wq[k * CH + c];
        ak += xv * Wk[k * CH + c];
        av += xv * Wv[k * CH + c];
    }
    qo[idx] = aq; ko[idx] = ak; vo[idx] = av;
}

// ---------------------------------------------------------------------------
// 6. Attention (online softmax) fused with o-projection + residual.
//    Block = 384 threads = 4 queries x 96 channels; r1 in-place over q.
// ---------------------------------------------------------------------------
__global__ __launch_bounds__(384) void attn_kernel(float* __restrict__ qr1,
                            const float* __restrict__ km, const float* __restrict__ vm,
                            const float* __restrict__ coord, const int* __restrict__ nbr,
                            const float* __restrict__ Wpos, const float* __restrict__ Wo,
                            const float* __restrict__ x) {
    __shared__ float wp[3 * CH];
    __shared__ float os[4][CH];
    for (int t = threadIdx.x; t < 3 * CH; t += 384) wp[t] = Wpos[t];
    __syncthreads();
    int lq = threadIdx.x / CH;
    int c = threadIdx.x - lq * CH;
    int qi = blockIdx.x * 4 + lq;           // global row 0..8191
    int b = qi >> 10, i = qi & 1023;
    const float* crd = coord + (size_t)b * NPTQ * 3;
    float cx = crd[(size_t)i * 3], cy = crd[(size_t)i * 3 + 1], cz = crd[(size_t)i * 3 + 2];
    float qv = qr1[(size_t)qi * CH + c];
    const int* nb = nbr + (size_t)qi * KNB;
    float m = -1e30f, l = 0.f, acc = 0.f;
    for (int t = 0; t < KNB; ++t) {
        int j = nb[t];                      // uniform across the row's 96 threads
        if (j < 0) break;                   // valid-first ordering
        float dx = cx - crd[(size_t)j * 3];
        float dy = cy - crd[(size_t)j * 3 + 1];
        float dz = cz - crd[(size_t)j * 3 + 2];
        float pe = dx * wp[c] + dy * wp[CH + c] + dz * wp[2 * CH + c];
        size_t row = (size_t)(b * NPTQ + j) * CH + c;
        float kn = km[row] + pe;
        float s = qv * kn;
        s += __shfl_xor(s, 1); s += __shfl_xor(s, 2);
        s += __shfl_xor(s, 4); s += __shfl_xor(s, 8);
        float logit = s * 0.25f;            // / sqrt(16)
        float mn = fmaxf(m, logit);
        float sc = expf(m - mn);
        float p = expf(logit - mn);
        float vn = vm[row] + pe;
        l = l * sc + p;
        acc = acc * sc + p * vn;
        m = mn;
    }
    os[lq][c] = (l > 0.f) ? acc / l : 0.f;  // self is always valid -> l >= 1
    __syncthreads();
    // r1 = x + attn_out @ Wo
    float r = x[(size_t)qi * CH + c];
    for (int k = 0; k < CH; ++k) r += os[lq][k] * Wo[k * CH + c];
    qr1[(size_t)qi * CH + c] = r;
}

// ---------------------------------------------------------------------------
// 7. LayerNorm (wave per row of 96)
// ---------------------------------------------------------------------------
__global__ void ln_kernel(const float* __restrict__ in, const float* __restrict__ g,
                          const float* __restrict__ be, float* __restrict__ out) {
    int row = blockIdx.x * 4 + (threadIdx.x >> 6);
    int lane = threadIdx.x & 63;
    const float* r = in + (size_t)row * CH;
    float e0 = r[lane];
    float e1 = (lane < 32) ? r[64 + lane] : 0.0f;
    float s = e0 + e1;
#pragma unroll
    for (int k = 32; k; k >>= 1) s += __shfl_xor(s, k);
    float mean = s * (1.0f / 96.0f);
    float d0 = e0 - mean, d1 = e1 - mean;
    float vs = d0 * d0 + ((lane < 32) ? d1 * d1 : 0.0f);
#pragma unroll
    for (int k = 32; k; k >>= 1) vs += __shfl_xor(vs, k);
    float rs = 1.0f / sqrtf(vs * (1.0f / 96.0f) + 1e-5f);
    float* o = out + (size_t)row * CH;
    o[lane] = d0 * rs * g[lane] + be[lane];
    if (lane < 32) o[64 + lane] = d1 * rs * g[64 + lane] + be[64 + lane];
}

// ---------------------------------------------------------------------------
// 8. Fused FFN, 4 rows per block (weight traffic /4):
//    r2 = x2 + relu(x2 @ W1 + b1) @ W2 + b2
// ---------------------------------------------------------------------------
__global__ __launch_bounds__(384) void ffn_kernel(const float* __restrict__ x2,
                           const float* __restrict__ W1, const float* __restrict__ b1,
                           const float* __restrict__ W2, const float* __restrict__ b2,
                           float* __restrict__ r2) {
    __shared__ float xs[4][CH];
    __shared__ float hs[4][FF];
    __shared__ float ps[4][4][CH];
    int row0 = blockIdx.x * 4, t = threadIdx.x;
    { int r = t / CH, c = t - (t / CH) * CH;
      xs[r][c] = x2[(size_t)(row0 + r) * CH + c]; }
    __syncthreads();
    {
        float bt = b1[t];
        float a0 = bt, a1 = bt, a2 = bt, a3 = bt;
        for (int k = 0; k < CH; ++k) {
            float w = W1[k * FF + t];
            a0 += xs[0][k] * w; a1 += xs[1][k] * w;
            a2 += xs[2][k] * w; a3 += xs[3][k] * w;
        }
        hs[0][t] = fmaxf(a0, 0.f); hs[1][t] = fmaxf(a1, 0.f);
        hs[2][t] = fmaxf(a2, 0.f); hs[3][t] = fmaxf(a3, 0.f);
    }
    __syncthreads();
    {
        int chunk = t / CH, c = t - (t / CH) * CH;
        float p0 = 0.f, p1 = 0.f, p2 = 0.f, p3 = 0.f;
        for (int m = chunk * CH; m < (chunk + 1) * CH; ++m) {
            float w = W2[m * CH + c];
            p0 += hs[0][m] * w; p1 += hs[1][m] * w;
            p2 += hs[2][m] * w; p3 += hs[3][m] * w;
        }
        ps[0][chunk][c] = p0; ps[1][chunk][c] = p1;
        ps[2][chunk][c] = p2; ps[3][chunk][c] = p3;
    }
    __syncthreads();
    { int r = t / CH, c = t - (t / CH) * CH;
      float rr = xs[r][c] + ((ps[r][0][c] + ps[r][1][c]) + (ps[r][2][c] + ps[r][3][c])) + b2[c];
      r2[(size_t)(row0 + r) * CH + c] = rr; }
}

// ---------------------------------------------------------------------------
// 9. LN2 + transposed fp32 store: out[b][c][i] = LN(r2)[b][i][c]
// ---------------------------------------------------------------------------
__global__ void ln2t_kernel(const float* __restrict__ in, const float* __restrict__ g,
                            const float* __restrict__ be, float* __restrict__ out) {
    int row = blockIdx.x * 4 + (threadIdx.x >> 6);
    int lane = threadIdx.x & 63;
    int b = row >> 10, i = row & 1023;
    const float* r = in + (size_t)row * CH;
    float e0 = r[lane];
    float e1 = (lane < 32) ? r[64 + lane] : 0.0f;
    float s = e0 + e1;
#pragma unroll
    for (int k = 32; k; k >>= 1) s += __shfl_xor(s, k);
    float mean = s * (1.0f / 96.0f);
    float d0 = e0 - mean, d1 = e1 - mean;
    float vs = d0 * d0 + ((lane < 32) ? d1 * d1 : 0.0f);
#pragma unroll
    for (int k = 32; k; k >>= 1) vs += __shfl_xor(vs, k);
    float rs = 1.0f / sqrtf(vs * (1.0f / 96.0f) + 1e-5f);
    float y0 = d0 * rs * g[lane] + be[lane];
    out[((size_t)(b * CH + lane)) * NPTQ + i] = scrub(y0);
    if (lane < 32) {
        float y1 = d1 * rs * g[64 + lane] + be[64 + lane];
        out[((size_t)(b * CH + 64 + lane)) * NPTQ + i] = scrub(y1);
    }
}

// ---------------------------------------------------------------------------
extern "C" void kernel_launch(void* const* d_in, const int* in_sizes, int n_in,
                              void* d_out, int out_size, void* d_ws, size_t ws_size,
                              hipStream_t stream) {
    const float* pc   = (const float*)d_in[0];
    const float* col  = (const float*)d_in[1];
    const float* Win  = (const float*)d_in[2];
    const float* bin  = (const float*)d_in[3];
    const float* Wq   = (const float*)d_in[4];
    const float* Wk   = (const float*)d_in[5];
    const float* Wv   = (const float*)d_in[6];
    const float* Wo   = (const float*)d_in[7];
    const float* Wpos = (const float*)d_in[8];
    const float* W1   = (const float*)d_in[9];
    const float* b1   = (const float*)d_in[10];
    const float* W2   = (const float*)d_in[11];
    const float* b2   = (const float*)d_in[12];
    const float* g1   = (const float*)d_in[13];
    const float* be1  = (const float*)d_in[14];
    const float* g2   = (const float*)d_in[15];
    const float* be2  = (const float*)d_in[16];
    const int*  sel   = (const int*)d_in[17];

    float* out_feat  = (float*)d_out;                      // 8*96*1024 fp32
    float* out_coord = out_feat + (size_t)B_ * CH * NPTQ;  // 8*1024*3 fp32

    // Workspace: ~13.8 MB total.
    char* ws = (char*)d_ws;
    size_t off = 0;
    auto alloc = [&](size_t bytes) { void* p = ws + off; off += (bytes + 255) & ~(size_t)255; return p; };
    int*   w_fps   = (int*)  alloc((size_t)B_ * NALL * 4);       //  38 KB
    float* w_coord = (float*)alloc((size_t)NQ * 3 * 4);          //  98 KB
    int*   w_nbr   = (int*)  alloc((size_t)NQ * KNB * 4);        // 1.1 MB
    float* w_x     = (float*)alloc((size_t)NQ * CH * 4);         // 3.1 MB
    float* w_q     = (float*)alloc((size_t)NQ * CH * 4);         // 3.1 MB (q -> r1 in-place)
    float* w_k     = (float*)alloc((size_t)NQ * CH * 4);         // 3.1 MB (k -> x2 after attn)
    float* w_v     = (float*)alloc((size_t)NQ * CH * 4);         // 3.1 MB (v -> r2 after attn)
    (void)ws_size; (void)in_sizes; (void)n_in; (void)out_size;

    fps_kernel<<<B_, FT, 0, stream>>>(pc, w_fps);
    gather_kernel<<<NQ / 256, 256, 0, stream>>>(pc, w_fps, sel, w_coord, out_coord);
    knn_kernel<<<NQ / 4, 256, 0, stream>>>(w_coord, w_nbr);
    xproj_kernel<<<NQ * CH / 256, 256, 0, stream>>>(pc, col, w_fps, sel, Win, bin, w_x);
    qkv_kernel<<<NQ * CH / 256, 256, 0, stream>>>(w_x, Wq, Wk, Wv, w_q, w_k, w_v);
    attn_kernel<<<NQ / 4, 384, 0, stream>>>(w_q, w_k, w_v, w_coord, w_nbr, Wpos, Wo, w_x);
    ln_kernel<<<NQ / 4, 256, 0, stream>>>(w_q, g1, be1, w_k);       // r1 -> x2
    ffn_kernel<<<NQ / 4, 384, 0, stream>>>(w_k, W1, b1, W2, b2, w_v);   // x2 -> r2
    ln2t_kernel<<<NQ / 4, 256, 0, stream>>>(w_v, g2, be2, out_feat);
}

// Round 9
// 2518.940 us; speedup vs baseline: 1.1038x; 1.1038x over previous
//
#include <hip/hip_runtime.h>
#include <math.h>

#define B_   8
#define NIN  20000
#define NALL 1200
#define NPTQ 1024
#define KNB  34
#define CH   96
#define FF   384
#define NQ   (B_ * NPTQ)   // 8192

#define FT   1024          // FPS threads per block
#define NPR  10            // float2 pairs per thread: 2*NPR*FT = 20480 >= 20000
#define NWAVE (FT / 64)    // 16 waves

typedef unsigned int   u32;
typedef unsigned long long u64;
typedef float v2f __attribute__((ext_vector_type(2)));

// Fast-math-proof non-finite check (integer ops can't be folded away).
__device__ __forceinline__ float scrub(float f) {
    u32 u = __float_as_uint(f);
    return ((u & 0x7F800000u) == 0x7F800000u) ? 12345.0f : f;   // diagnostic sentinel
}

// ---------------------------------------------------------------------------
// 1. Farthest point sampling: one block per batch (rounds 1-4: cross-block
//    handshakes >= 2.4us/iter at device scope -- dead end).
//    Register-residency ledger: 512thr -> 104/116 granted no matter the hint
//    (rounds 0/5/6); 1024thr no-hint -> 64 (round 7); 1024thr+(FT,4) -> 52
//    (round 8, 52 = all it needed).  Round 8 also showed the LDS-resident
//    alternative is LDS-pipe-bound (160KB/iter ~= 1900cyc > the spill path).
//    Synthesis: the backend never targets < 4 waves/EU unless the block size
//    makes that the structural minimum -- which a 1024-thread block DOES
//    (16 waves = exactly 4/EU = 1 block/CU).  So at 1024 threads the 128-VGPR
//    cap is reachable: 80 data VGPRs (10 v2f x px,py,pz,dist) + ~25 working
//    ~= 105 <= 128.  This round = round-7 kernel + the occupancy pin
//    __launch_bounds__(FT,4) + amdgpu_waves_per_eu(4,4).  VGPR_Count ~100+
//    is the decisive signal; ~64 again means register residency is dead.
//    Argmax is value-first: inner loop tracks only the pk max; index is
//    recovered after block max M is known by equality scan (exact: min/max
//    return an operand bit-identically) in waves containing M only.
//    Exactness: rn ops in numpy order (contract off), min/max order-
//    independent; winner = smallest point index among value-ties
//    (idx = slot*1024 + tid is lexicographic (slot,tid)) = jnp.argmax's
//    first-occurrence semantics.  Pads carry dist=-1 (< any real d2 >= 0,
//    never equal to M >= 0).
// ---------------------------------------------------------------------------
__global__ __launch_bounds__(FT, 4)
__attribute__((amdgpu_waves_per_eu(4, 4)))
void fps_kernel(const float* __restrict__ pc, int* __restrict__ fps_idx) {
#pragma clang fp contract(off)
    const int b = blockIdx.x;
    const int tid = threadIdx.x;
    const int lane = tid & 63;
    const int wid = tid >> 6;          // 0..15
    const float* base = pc + (size_t)b * NIN * 3;

    v2f px[NPR], py[NPR], pz[NPR], dist[NPR];
#pragma unroll
    for (int j = 0; j < NPR; ++j) {
        int i0 = tid + (2 * j) * FT;   // max 19455: always valid
        int i1 = i0 + FT;              // max 20479: padded when >= NIN
        bool ok1 = i1 < NIN;
        int a1 = ok1 ? i1 : 0;
        float x0 = base[(size_t)i0 * 3 + 0];
        float y0 = base[(size_t)i0 * 3 + 1];
        float z0 = base[(size_t)i0 * 3 + 2];
        float x1 = base[(size_t)a1 * 3 + 0];
        float y1 = base[(size_t)a1 * 3 + 1];
        float z1 = base[(size_t)a1 * 3 + 2];
        // opaque-register pin: compiler cannot rematerialize these from pc
        asm volatile("" : "+v"(x0), "+v"(y0), "+v"(z0), "+v"(x1), "+v"(y1), "+v"(z1));
        px[j].x = x0; px[j].y = x1;
        py[j].x = y0; py[j].y = y1;
        pz[j].x = z0; pz[j].y = z1;
        dist[j].x = 1e10f;
        dist[j].y = ok1 ? 1e10f : -1.0f;   // pad: never wins, never equals M
    }

    __shared__ float wmax[2][NWAVE];
    __shared__ u32 widx_s[2];

    if (tid == 0) {
        widx_s[0] = 0xFFFFFFFFu;
        widx_s[1] = 0xFFFFFFFFu;
        fps_idx[b * NALL + 0] = 0;
    }
    __syncthreads();
    float cx = base[0], cy = base[1], cz = base[2];

    for (int it = 1; it < NALL; ++it) {
        const int pb = it & 1;
        v2f cvx; cvx.x = cx; cvx.y = cx;
        v2f cvy; cvy.x = cy; cvy.y = cy;
        v2f cvz; cvz.x = cz; cvz.y = cz;
        v2f run; run.x = -1e38f; run.y = -1e38f;
#pragma unroll
        for (int j = 0; j < NPR; ++j) {
            v2f dx = px[j] - cvx;
            v2f dy = py[j] - cvy;
            v2f dz = pz[j] - cvz;
            v2f sx = dx * dx;
            v2f sy = dy * dy;
            v2f sz = dz * dz;
            v2f d  = (sx + sy) + sz;          // exact numpy order, no FMA
            v2f nd = __builtin_elementwise_min(dist[j], d);
            dist[j] = nd;
            run = __builtin_elementwise_max(run, nd);
        }
        float lm = fmaxf(run.x, run.y);
        // wave f32 max (6-step butterfly)
        float wm = lm;
#pragma unroll
        for (int s = 32; s; s >>= 1) wm = fmaxf(wm, __shfl_xor(wm, s, 64));
        if (lane == 0) wmax[pb][wid] = wm;
        __syncthreads();                       // barrier 1
        if (tid == 0) widx_s[pb ^ 1] = 0xFFFFFFFFu;  // reset idle buffer (safe here)
        float M = wmax[pb][0];
#pragma unroll
        for (int w = 1; w < NWAVE; ++w) M = fmaxf(M, wmax[pb][w]);

        // index recovery: only waves containing M scan + reduce
        if (__any(lm == M)) {
            u32 msk = 0;
#pragma unroll
            for (int j = 0; j < NPR; ++j) {
                if (dist[j].x == M) msk |= (1u << (2 * j));
                if (dist[j].y == M) msk |= (1u << (2 * j + 1));
            }
            // sentinel bit 31: lanes w/o match yield slot 31 -> idx >= 31744,
            // always loses to a real candidate (<= 20479); some lane here has one.
            u32 slot = (u32)__builtin_ctz(msk | 0x80000000u);
            u32 cand = slot * (u32)FT + (u32)tid;    // == global point index
#pragma unroll
            for (int s = 32; s; s >>= 1) {
                u32 o = (u32)__shfl_xor((int)cand, s, 64);
                cand = (o < cand) ? o : cand;
            }
            if (lane == 0) atomicMin(&widx_s[pb], cand);
        }
        __syncthreads();                       // barrier 2
        u32 widx = widx_s[pb];
        widx = (widx < NIN) ? widx : 0;        // defensive (cannot trigger)
        if (tid == 0) fps_idx[b * NALL + it] = (int)widx;
        const float* wp = base + (size_t)widx * 3;
        cx = wp[0]; cy = wp[1]; cz = wp[2];    // same addr all lanes: broadcast
    }
}

// ---------------------------------------------------------------------------
// 2. Gather coords at fps_idx[sel]; fp32 coord workspace + fp32 coord output
// ---------------------------------------------------------------------------
__global__ void gather_kernel(const float* __restrict__ pc,
                              const int* __restrict__ fps_idx, const int* __restrict__ sel,
                              float* __restrict__ coord, float* __restrict__ out_coord) {
    int t = blockIdx.x * 256 + threadIdx.x;
    if (t >= NQ) return;
    int b = t >> 10, j = t & 1023;
    int p = fps_idx[b * NALL + sel[j]];
    p = (p < 0) ? 0 : ((p >= NIN) ? (NIN - 1) : p);   // defensive clamp
    const float* pp = pc + ((size_t)b * NIN + p) * 3;
    float x = pp[0], y = pp[1], z = pp[2];
    coord[(size_t)t * 3 + 0] = x;
    coord[(size_t)t * 3 + 1] = y;
    coord[(size_t)t * 3 + 2] = z;
    out_coord[(size_t)t * 3 + 0] = scrub(x);
    out_coord[(size_t)t * 3 + 1] = scrub(y);
    out_coord[(size_t)t * 3 + 2] = scrub(z);
}

// ---------------------------------------------------------------------------
// 3. kNN within radius: one wave per query, stable (d2, idx) ascending, K=34.
// ---------------------------------------------------------------------------
__global__ void knn_kernel(const float* __restrict__ coord, int* __restrict__ nbr) {
    __shared__ float sx[NPTQ], sy[NPTQ], sz[NPTQ];
    const double RAD2D = (2.5 * 0.04) * (2.5 * 0.04);
    int b = blockIdx.x >> 8;              // 256 blocks per batch
    int i0 = (blockIdx.x & 255) * 4;
    const float* cb = coord + (size_t)b * NPTQ * 3;
    for (int t = threadIdx.x; t < NPTQ; t += 256) {
        sx[t] = cb[(size_t)t * 3 + 0];
        sy[t] = cb[(size_t)t * 3 + 1];
        sz[t] = cb[(size_t)t * 3 + 2];
    }
    __syncthreads();
    int wid = threadIdx.x >> 6, lane = threadIdx.x & 63;
    int i = i0 + wid;
    float qx = sx[i], qy = sy[i], qz = sz[i];
    u64 pk[16];
#pragma unroll
    for (int t = 0; t < 16; ++t) {
        int j = lane + t * 64;
        float dx = __fsub_rn(qx, sx[j]);
        float dy = __fsub_rn(qy, sy[j]);
        float dz = __fsub_rn(qz, sz[j]);
        float d2 = __fadd_rn(__fadd_rn(__fmul_rn(dx, dx), __fmul_rn(dy, dy)),
                             __fmul_rn(dz, dz));
        bool valid = ((double)d2 <= RAD2D);
        pk[t] = valid ? (((u64)__float_as_uint(d2) << 32) | (u32)j) : ~0ull;
    }
    int* out = nbr + ((size_t)b * NPTQ + i) * KNB;
    int k = 0;
    for (; k < KNB; ++k) {
        u64 m = ~0ull;
#pragma unroll
        for (int t = 0; t < 16; ++t) m = (pk[t] < m) ? pk[t] : m;
#pragma unroll
        for (int s = 32; s; s >>= 1) {
            u64 o = __shfl_xor(m, s, 64);
            m = (o < m) ? o : m;
        }
        if (m == ~0ull) break;
#pragma unroll
        for (int t = 0; t < 16; ++t) if (pk[t] == m) pk[t] = ~0ull;
        if (lane == 0) out[k] = (int)(m & 0xFFFFFFFFu);
    }
    for (; k < KNB; ++k) if (lane == 0) out[k] = -1;
}

// ---------------------------------------------------------------------------
// 4. x = [color, coord] @ W_in + b_in  (reads inputs directly via fps_idx/sel)
// ---------------------------------------------------------------------------
__global__ void xproj_kernel(const float* __restrict__ pc, const float* __restrict__ col,
                             const int* __restrict__ fps_idx, const int* __restrict__ sel,
                             const float* __restrict__ Win, const float* __restrict__ bin,
                             float* __restrict__ x) {
    int idx = blockIdx.x * 256 + threadIdx.x;
    if (idx >= NQ * CH) return;
    int q = idx / CH, c = idx - q * CH;
    int b = q >> 10, j = q & 1023;
    int p = fps_idx[b * NALL + sel[j]];
    p = (p < 0) ? 0 : ((p >= NIN) ? (NIN - 1) : p);
    const float* pp = pc + ((size_t)b * NIN + p) * 3;
    const float* cc = col + ((size_t)b * NIN + p) * 3;
    float acc = bin[c];
    acc += cc[0] * Win[0 * CH + c];
    acc += cc[1] * Win[1 * CH + c];
    acc += cc[2] * Win[2 * CH + c];
    acc += pp[0] * Win[3 * CH + c];
    acc += pp[1] * Win[4 * CH + c];
    acc += pp[2] * Win[5 * CH + c];
    x[idx] = acc;
}

// ---------------------------------------------------------------------------
// 5. q,k,v = x @ Wq/Wk/Wv  (computed once per point)
// ---------------------------------------------------------------------------
__global__ void qkv_kernel(const float* __restrict__ x,
                           const float* __restrict__ Wq, const float* __restrict__ Wk,
                           const float* __restrict__ Wv,
                           float* __restrict__ qo, float* __restrict__ ko,
                           float* __restrict__ vo) {
    int idx = blockIdx.x * 256 + threadIdx.x;
    if (idx >= NQ * CH) return;
    int q = idx / CH, c = idx - q * CH;
    const float* xr = x + (size_t)q * CH;
    float aq = 0.f, ak = 0.f, av = 0.f;
    for (int k = 0; k < CH; ++k) {
        float xv = xr[k];
        aq += xv * Wq[k * CH + c];
        ak += xv * Wk[k * CH + c];
        av += xv * Wv[k * CH + c];
    }
    qo[idx] = aq; ko[idx] = ak; vo[idx] = av;
}

// ---------------------------------------------------------------------------
// 6. Attention (online softmax) fused with o-projection + residual.
//    Block = 384 threads = 4 queries x 96 channels; r1 in-place over q.
// ---------------------------------------------------------------------------
__global__ __launch_bounds__(384) void attn_kernel(float* __restrict__ qr1,
                            const float* __restrict__ km, const float* __restrict__ vm,
                            const float* __restrict__ coord, const int* __restrict__ nbr,
                            const float* __restrict__ Wpos, const float* __restrict__ Wo,
                            const float* __restrict__ x) {
    __shared__ float wp[3 * CH];
    __shared__ float os[4][CH];
    for (int t = threadIdx.x; t < 3 * CH; t += 384) wp[t] = Wpos[t];
    __syncthreads();
    int lq = threadIdx.x / CH;
    int c = threadIdx.x - lq * CH;
    int qi = blockIdx.x * 4 + lq;           // global row 0..8191
    int b = qi >> 10, i = qi & 1023;
    const float* crd = coord + (size_t)b * NPTQ * 3;
    float cx = crd[(size_t)i * 3], cy = crd[(size_t)i * 3 + 1], cz = crd[(size_t)i * 3 + 2];
    float qv = qr1[(size_t)qi * CH + c];
    const int* nb = nbr + (size_t)qi * KNB;
    float m = -1e30f, l = 0.f, acc = 0.f;
    for (int t = 0; t < KNB; ++t) {
        int j = nb[t];                      // uniform across the row's 96 threads
        if (j < 0) break;                   // valid-first ordering
        float dx = cx - crd[(size_t)j * 3];
        float dy = cy - crd[(size_t)j * 3 + 1];
        float dz = cz - crd[(size_t)j * 3 + 2];
        float pe = dx * wp[c] + dy * wp[CH + c] + dz * wp[2 * CH + c];
        size_t row = (size_t)(b * NPTQ + j) * CH + c;
        float kn = km[row] + pe;
        float s = qv * kn;
        s += __shfl_xor(s, 1); s += __shfl_xor(s, 2);
        s += __shfl_xor(s, 4); s += __shfl_xor(s, 8);
        float logit = s * 0.25f;            // / sqrt(16)
        float mn = fmaxf(m, logit);
        float sc = expf(m - mn);
        float p = expf(logit - mn);
        float vn = vm[row] + pe;
        l = l * sc + p;
        acc = acc * sc + p * vn;
        m = mn;
    }
    os[lq][c] = (l > 0.f) ? acc / l : 0.f;  // self is always valid -> l >= 1
    __syncthreads();
    // r1 = x + attn_out @ Wo
    float r = x[(size_t)qi * CH + c];
    for (int k = 0; k < CH; ++k) r += os[lq][k] * Wo[k * CH + c];
    qr1[(size_t)qi * CH + c] = r;
}

// ---------------------------------------------------------------------------
// 7. LayerNorm (wave per row of 96)
// ---------------------------------------------------------------------------
__global__ void ln_kernel(const float* __restrict__ in, const float* __restrict__ g,
                          const float* __restrict__ be, float* __restrict__ out) {
    int row = blockIdx.x * 4 + (threadIdx.x >> 6);
    int lane = threadIdx.x & 63;
    const float* r = in + (size_t)row * CH;
    float e0 = r[lane];
    float e1 = (lane < 32) ? r[64 + lane] : 0.0f;
    float s = e0 + e1;
#pragma unroll
    for (int k = 32; k; k >>= 1) s += __shfl_xor(s, k);
    float mean = s * (1.0f / 96.0f);
    float d0 = e0 - mean, d1 = e1 - mean;
    float vs = d0 * d0 + ((lane < 32) ? d1 * d1 : 0.0f);
#pragma unroll
    for (int k = 32; k; k >>= 1) vs += __shfl_xor(vs, k);
    float rs = 1.0f / sqrtf(vs * (1.0f / 96.0f) + 1e-5f);
    float* o = out + (size_t)row * CH;
    o[lane] = d0 * rs * g[lane] + be[lane];
    if (lane < 32) o[64 + lane] = d1 * rs * g[64 + lane] + be[64 + lane];
}

// ---------------------------------------------------------------------------
// 8. Fused FFN, 4 rows per block (weight traffic /4):
//    r2 = x2 + relu(x2 @ W1 + b1) @ W2 + b2
// ---------------------------------------------------------------------------
__global__ __launch_bounds__(384) void ffn_kernel(const float* __restrict__ x2,
                           const float* __restrict__ W1, const float* __restrict__ b1,
                           const float* __restrict__ W2, const float* __restrict__ b2,
                           float* __restrict__ r2) {
    __shared__ float xs[4][CH];
    __shared__ float hs[4][FF];
    __shared__ float ps[4][4][CH];
    int row0 = blockIdx.x * 4, t = threadIdx.x;
    { int r = t / CH, c = t - (t / CH) * CH;
      xs[r][c] = x2[(size_t)(row0 + r) * CH + c]; }
    __syncthreads();
    {
        float bt = b1[t];
        float a0 = bt, a1 = bt, a2 = bt, a3 = bt;
        for (int k = 0; k < CH; ++k) {
            float w = W1[k * FF + t];
            a0 += xs[0][k] * w; a1 += xs[1][k] * w;
            a2 += xs[2][k] * w; a3 += xs[3][k] * w;
        }
        hs[0][t] = fmaxf(a0, 0.f); hs[1][t] = fmaxf(a1, 0.f);
        hs[2][t] = fmaxf(a2, 0.f); hs[3][t] = fmaxf(a3, 0.f);
    }
    __syncthreads();
    {
        int chunk = t / CH, c = t - (t / CH) * CH;
        float p0 = 0.f, p1 = 0.f, p2 = 0.f, p3 = 0.f;
        for (int m = chunk * CH; m < (chunk + 1) * CH; ++m) {
            float w = W2[m * CH + c];
            p0 += hs[0][m] * w; p1 += hs[1][m] * w;
            p2 += hs[2][m] * w; p3 += hs[3][m] * w;
        }
        ps[0][chunk][c] = p0; ps[1][chunk][c] = p1;
        ps[2][chunk][c] = p2; ps[3][chunk][c] = p3;
    }
    __syncthreads();
    { int r = t / CH, c = t - (t / CH) * CH;
      float rr = xs[r][c] + ((ps[r][0][c] + ps[r][1][c]) + (ps[r][2][c] + ps[r][3][c])) + b2[c];
      r2[(size_t)(row0 + r) * CH + c] = rr; }
}

// ---------------------------------------------------------------------------
// 9. LN2 + transposed fp32 store: out[b][c][i] = LN(r2)[b][i][c]
// ---------------------------------------------------------------------------
__global__ void ln2t_kernel(const float* __restrict__ in, const float* __restrict__ g,
                            const float* __restrict__ be, float* __restrict__ out) {
    int row = blockIdx.x * 4 + (threadIdx.x >> 6);
    int lane = threadIdx.x & 63;
    int b = row >> 10, i = row & 1023;
    const float* r = in + (size_t)row * CH;
    float e0 = r[lane];
    float e1 = (lane < 32) ? r[64 + lane] : 0.0f;
    float s = e0 + e1;
#pragma unroll
    for (int k = 32; k; k >>= 1) s += __shfl_xor(s, k);
    float mean = s * (1.0f / 96.0f);
    float d0 = e0 - mean, d1 = e1 - mean;
    float vs = d0 * d0 + ((lane < 32) ? d1 * d1 : 0.0f);
#pragma unroll
    for (int k = 32; k; k >>= 1) vs += __shfl_xor(vs, k);
    float rs = 1.0f / sqrtf(vs * (1.0f / 96.0f) + 1e-5f);
    float y0 = d0 * rs * g[lane] + be[lane];
    out[((size_t)(b * CH + lane)) * NPTQ + i] = scrub(y0);
    if (lane < 32) {
        float y1 = d1 * rs * g[64 + lane] + be[64 + lane];
        out[((size_t)(b * CH + 64 + lane)) * NPTQ + i] = scrub(y1);
    }
}

// ---------------------------------------------------------------------------
extern "C" void kernel_launch(void* const* d_in, const int* in_sizes, int n_in,
                              void* d_out, int out_size, void* d_ws, size_t ws_size,
                              hipStream_t stream) {
    const float* pc   = (const float*)d_in[0];
    const float* col  = (const float*)d_in[1];
    const float* Win  = (const float*)d_in[2];
    const float* bin  = (const float*)d_in[3];
    const float* Wq   = (const float*)d_in[4];
    const float* Wk   = (const float*)d_in[5];
    const float* Wv   = (const float*)d_in[6];
    const float* Wo   = (const float*)d_in[7];
    const float* Wpos = (const float*)d_in[8];
    const float* W1   = (const float*)d_in[9];
    const float* b1   = (const float*)d_in[10];
    const float* W2   = (const float*)d_in[11];
    const float* b2   = (const float*)d_in[12];
    const float* g1   = (const float*)d_in[13];
    const float* be1  = (const float*)d_in[14];
    const float* g2   = (const float*)d_in[15];
    const float* be2  = (const float*)d_in[16];
    const int*  sel   = (const int*)d_in[17];

    float* out_feat  = (float*)d_out;                      // 8*96*1024 fp32
    float* out_coord = out_feat + (size_t)B_ * CH * NPTQ;  // 8*1024*3 fp32

    // Workspace: ~13.8 MB total.
    char* ws = (char*)d_ws;
    size_t off = 0;
    auto alloc = [&](size_t bytes) { void* p = ws + off; off += (bytes + 255) & ~(size_t)255; return p; };
    int*   w_fps   = (int*)  alloc((size_t)B_ * NALL * 4);       //  38 KB
    float* w_coord = (float*)alloc((size_t)NQ * 3 * 4);          //  98 KB
    int*   w_nbr   = (int*)  alloc((size_t)NQ * KNB * 4);        // 1.1 MB
    float* w_x     = (float*)alloc((size_t)NQ * CH * 4);         // 3.1 MB
    float* w_q     = (float*)alloc((size_t)NQ * CH * 4);         // 3.1 MB (q -> r1 in-place)
    float* w_k     = (float*)alloc((size_t)NQ * CH * 4);         // 3.1 MB (k -> x2 after attn)
    float* w_v     = (float*)alloc((size_t)NQ * CH * 4);         // 3.1 MB (v -> r2 after attn)
    (void)ws_size; (void)in_sizes; (void)n_in; (void)out_size;

    fps_kernel<<<B_, FT, 0, stream>>>(pc, w_fps);
    gather_kernel<<<NQ / 256, 256, 0, stream>>>(pc, w_fps, sel, w_coord, out_coord);
    knn_kernel<<<NQ / 4, 256, 0, stream>>>(w_coord, w_nbr);
    xproj_kernel<<<NQ * CH / 256, 256, 0, stream>>>(pc, col, w_fps, sel, Win, bin, w_x);
    qkv_kernel<<<NQ * CH / 256, 256, 0, stream>>>(w_x, Wq, Wk, Wv, w_q, w_k, w_v);
    attn_kernel<<<NQ / 4, 384, 0, stream>>>(w_q, w_k, w_v, w_coord, w_nbr, Wpos, Wo, w_x);
    ln_kernel<<<NQ / 4, 256, 0, stream>>>(w_q, g1, be1, w_k);       // r1 -> x2
    ffn_kernel<<<NQ / 4, 384, 0, stream>>>(w_k, W1, b1, W2, b2, w_v);   // x2 -> r2
    ln2t_kernel<<<NQ / 4, 256, 0, stream>>>(w_v, g2, be2, out_feat);
}